// Round 6
// baseline (356.314 us; speedup 1.0000x reference)
//
#include <hip/hip_runtime.h>
#include <hip/hip_bf16.h>

#define BB 16
#define TT 512
#define DD 64
#define HH 128
#define SS 100
#define MSZ 20
#define NROW (BB*TT)      // 8192
#define FOURH 512

typedef __attribute__((ext_vector_type(8))) short bh8;   // 8 bf16 in 4 VGPRs
typedef __attribute__((ext_vector_type(4))) float fv4;   // MFMA accumulator

__device__ __forceinline__ float frcp(float x){ return __builtin_amdgcn_rcpf(x); }
__device__ __forceinline__ float sigmoidf_(float x){
    return frcp(1.0f + __expf(-x));
}
__device__ __forceinline__ float tanhf_(float x){
    float t = __expf(2.0f * x);
    return 1.0f - 2.0f * frcp(t + 1.0f);   // rcp(inf)=0 -> saturates to +/-1
}
__device__ __forceinline__ unsigned short f2bf(float f){
    __hip_bfloat16 h = __float2bfloat16(f);   // RNE
    union { __hip_bfloat16 b; unsigned short u; } cv; cv.b = h;
    return cv.u;
}

// ---------------- kernel A: xw = inputs @ lstm_kernel + bias ----------------
// Output layout: xw[row][n*4 + g]  (gate-interleaved per neuron -> float4/step
// loads in k_scan). row = b*TT + t, n = 0..127, g = i,f,g,o.
__global__ __launch_bounds__(512) void k_xw(const float* __restrict__ inp,
        const float* __restrict__ Wk, const float* __restrict__ bias,
        float* __restrict__ xw){
    __shared__ float in_s[8 * DD];
    int tid = threadIdx.x;
    int r0 = blockIdx.x * 8;
    in_s[tid] = inp[(size_t)r0 * DD + tid];
    __syncthreads();
    int j = tid;                       // original column g*128 + n
    int n = j & 127, g = j >> 7;
    float wreg[DD];
    #pragma unroll
    for (int d = 0; d < DD; ++d) wreg[d] = Wk[d * FOURH + j];
    float bv = bias[j];
    const float4* in4 = reinterpret_cast<const float4*>(in_s);
    #pragma unroll
    for (int r = 0; r < 8; ++r){
        float acc = bv;
        #pragma unroll
        for (int q = 0; q < DD/4; ++q){
            float4 iv = in4[r*(DD/4) + q];
            acc = fmaf(iv.x, wreg[4*q+0], acc);
            acc = fmaf(iv.y, wreg[4*q+1], acc);
            acc = fmaf(iv.z, wreg[4*q+2], acc);
            acc = fmaf(iv.w, wreg[4*q+3], acc);
        }
        xw[(size_t)(r0 + r) * FOURH + n*4 + g] = acc;
    }
}

// ---------------- kernel B: LSTM scan via MFMA, ONE block PER BATCH ---------
// (1x128 h) @ (128x512 Rk) per step as 16x16x32 MFMA with A-rows 1..15 == 0.
// Key: those rows are STRUCTURALLY zero -> only lanes with (l&15)==0 read h
// from LDS (4 lanes/wave, 4 distinct 16B slots, conflict-free); all other
// lanes supply zero A-fragments from registers. h buffer is 128 bf16 (256 B),
// double-buffered. xw is loaded as ONE float4 per step (gate-interleaved
// layout from k_xw) and folded into the MFMA C-init. One barrier per step.
__global__ __launch_bounds__(512, 2) void k_scan(const float* __restrict__ xw,
        const float* __restrict__ Rk, float* __restrict__ ctrl){
    __shared__ __align__(16) unsigned short hb[2][HH];   // 2 x 128 bf16
    const int tid = threadIdx.x;
    const int b  = blockIdx.x;   // batch
    const int w  = tid >> 6;     // wave 0..7
    const int l  = tid & 63;
    const int q  = l >> 4;       // k-group 0..3
    const int lo = l & 15;       // A-row / C-col
    if (tid < 2*HH) hb[tid >> 7][tid & 127] = 0;
    // ---- Rk B-fragments (bf16), resident in VGPRs: 64 VGPRs ----
    bh8 bf[4][4];
    #pragma unroll
    for (int Ti = 0; Ti < 4; ++Ti){
        const int col = Ti*128 + w*16 + lo;
        #pragma unroll
        for (int kk = 0; kk < 4; ++kk){
            union { unsigned short us[8]; bh8 v; } u;
            #pragma unroll
            for (int j = 0; j < 8; ++j)
                u.us[j] = f2bf(Rk[(size_t)(kk*32 + q*8 + j)*FOURH + col]);
            bf[Ti][kk] = u.v;
        }
    }
    const bool upd = (q == 0);          // lanes 0..15: own neuron n = 16w+lo
    const bool rdh = (lo == 0);         // lanes 0,16,32,48: carry real A data
    const int  n   = w*16 + lo;
    const float4* xb4 = reinterpret_cast<const float4*>(xw) + (size_t)b*TT*HH + n;
    float c0 = 0.0f;
    float4 xc = upd ? xb4[0] : make_float4(0.f,0.f,0.f,0.f);
    __syncthreads();
    int p = 0;
    for (int t = 0; t < TT; ++t){
        union { uint4 u; bh8 v; } a0, a1, a2, a3;
        a0.u = make_uint4(0u,0u,0u,0u);
        a1.u = a0.u; a2.u = a0.u; a3.u = a0.u;
        if (rdh){
            const uint4* hr = reinterpret_cast<const uint4*>(&hb[p][0]); // 16B slots
            a0.u = hr[q];          // k = 8q      + 0
            a1.u = hr[q + 4];      // k = 8q + 32
            a2.u = hr[q + 8];      // k = 8q + 64
            a3.u = hr[q + 12];     // k = 8q + 96
        }
        // prefetch next step's xw (one dwordx4, hidden under MFMA)
        const int tn = (t+1 < TT) ? t+1 : t;
        float4 xn = upd ? xb4[(size_t)tn * HH] : make_float4(0.f,0.f,0.f,0.f);
        // C-init = xw (row 0 lives in reg 0 of q==0 lanes); rows 1..15 = 0
        fv4 z0 = {upd ? xc.x : 0.f, 0.f, 0.f, 0.f};
        fv4 z1 = {upd ? xc.y : 0.f, 0.f, 0.f, 0.f};
        fv4 z2 = {upd ? xc.z : 0.f, 0.f, 0.f, 0.f};
        fv4 z3 = {upd ? xc.w : 0.f, 0.f, 0.f, 0.f};
        z0 = __builtin_amdgcn_mfma_f32_16x16x32_bf16(a0.v, bf[0][0], z0, 0,0,0);
        z1 = __builtin_amdgcn_mfma_f32_16x16x32_bf16(a0.v, bf[1][0], z1, 0,0,0);
        z2 = __builtin_amdgcn_mfma_f32_16x16x32_bf16(a0.v, bf[2][0], z2, 0,0,0);
        z3 = __builtin_amdgcn_mfma_f32_16x16x32_bf16(a0.v, bf[3][0], z3, 0,0,0);
        z0 = __builtin_amdgcn_mfma_f32_16x16x32_bf16(a1.v, bf[0][1], z0, 0,0,0);
        z1 = __builtin_amdgcn_mfma_f32_16x16x32_bf16(a1.v, bf[1][1], z1, 0,0,0);
        z2 = __builtin_amdgcn_mfma_f32_16x16x32_bf16(a1.v, bf[2][1], z2, 0,0,0);
        z3 = __builtin_amdgcn_mfma_f32_16x16x32_bf16(a1.v, bf[3][1], z3, 0,0,0);
        z0 = __builtin_amdgcn_mfma_f32_16x16x32_bf16(a2.v, bf[0][2], z0, 0,0,0);
        z1 = __builtin_amdgcn_mfma_f32_16x16x32_bf16(a2.v, bf[1][2], z1, 0,0,0);
        z2 = __builtin_amdgcn_mfma_f32_16x16x32_bf16(a2.v, bf[2][2], z2, 0,0,0);
        z3 = __builtin_amdgcn_mfma_f32_16x16x32_bf16(a2.v, bf[3][2], z3, 0,0,0);
        z0 = __builtin_amdgcn_mfma_f32_16x16x32_bf16(a3.v, bf[0][3], z0, 0,0,0);
        z1 = __builtin_amdgcn_mfma_f32_16x16x32_bf16(a3.v, bf[1][3], z1, 0,0,0);
        z2 = __builtin_amdgcn_mfma_f32_16x16x32_bf16(a3.v, bf[2][3], z2, 0,0,0);
        z3 = __builtin_amdgcn_mfma_f32_16x16x32_bf16(a3.v, bf[3][3], z3, 0,0,0);
        if (upd){
            float ig = sigmoidf_(z0[0]);
            float fg = sigmoidf_(z1[0]);
            float gg = tanhf_   (z2[0]);
            float og = sigmoidf_(z3[0]);
            c0 = fg * c0 + ig * gg;
            float h = og * tanhf_(c0);
            ctrl[((size_t)b*TT + t)*HH + n] = h;
            hb[p ^ 1][n] = f2bf(h);
            xc = xn;
        }
        p ^= 1;
        __syncthreads();
    }
}

// ---------------- kernel C: proj = ctrl @ [8 heads' W] + biases; also copies
// ctrl into out[:, 0:128] ----------------------------------------------------
__global__ __launch_bounds__(320) void k_proj(const float* __restrict__ ctrl,
        const float* __restrict__ rWk, const float* __restrict__ rbk,
        const float* __restrict__ wWk, const float* __restrict__ wbk,
        const float* __restrict__ wWe, const float* __restrict__ wbe,
        const float* __restrict__ wWa, const float* __restrict__ wba,
        float* __restrict__ proj, float* __restrict__ out){
    __shared__ float cs[16 * HH];
    int tid = threadIdx.x;
    int r0 = blockIdx.x * 16;
    for (int idx = tid; idx < 16 * HH; idx += 320){
        float v = ctrl[(size_t)r0 * HH + idx];
        cs[idx] = v;
        int r = idx >> 7, k = idx & 127;
        out[(size_t)(r0 + r) * 168 + k] = v;
    }
    __syncthreads();
    int j = tid % 160;
    int rh = tid / 160;
    int p = j / MSZ, m = j % MSZ;
    const float* Wp; const float* bp;
    switch (p){
        case 0:  Wp = rWk;            bp = rbk;        break;
        case 1:  Wp = rWk + HH*MSZ;   bp = rbk + MSZ;  break;
        case 2:  Wp = wWk;            bp = wbk;        break;
        case 3:  Wp = wWk + HH*MSZ;   bp = wbk + MSZ;  break;
        case 4:  Wp = wWe;            bp = wbe;        break;
        case 5:  Wp = wWe + HH*MSZ;   bp = wbe + MSZ;  break;
        case 6:  Wp = wWa;            bp = wba;        break;
        default: Wp = wWa + HH*MSZ;   bp = wba + MSZ;  break;
    }
    float wv[HH];
    #pragma unroll
    for (int k = 0; k < HH; ++k) wv[k] = Wp[k * MSZ + m];
    float bv = bp[m];
    #pragma unroll
    for (int r = 0; r < 8; ++r){
        int row = rh * 8 + r;
        float acc = bv;
        const float4* c4 = reinterpret_cast<const float4*>(cs + row * HH);
        #pragma unroll
        for (int q = 0; q < HH/4; ++q){
            float4 cv = c4[q];
            acc = fmaf(cv.x, wv[4*q+0], acc);
            acc = fmaf(cv.y, wv[4*q+1], acc);
            acc = fmaf(cv.z, wv[4*q+2], acc);
            acc = fmaf(cv.w, wv[4*q+3], acc);
        }
        proj[(size_t)(r0 + row) * 160 + j] = acc;
    }
}

// ---------------- kernel D: heads, one block per (b,t) ----------------------
__device__ __forceinline__ float blocksum128(float v, float* red){
    #pragma unroll
    for (int o = 1; o < 64; o <<= 1) v += __shfl_xor(v, o, 64);
    int tid = threadIdx.x;
    if ((tid & 63) == 0) red[tid >> 6] = v;
    __syncthreads();
    float s = red[0] + red[1];
    __syncthreads();
    return s;
}

__global__ __launch_bounds__(128) void k_heads(const float* __restrict__ proj,
        const float* __restrict__ memory, float* __restrict__ out,
        float* __restrict__ outmem){
    __shared__ float mem0[SS * MSZ];
    __shared__ float rn[SS];
    __shared__ float khat[4][MSZ];
    __shared__ float ea[4][MSZ];
    __shared__ float wrd[2][SS];
    __shared__ float red[2];
    __shared__ float pz[160];
    int tid = threadIdx.x;
    int bt = blockIdx.x;
    for (int idx = tid; idx < SS * MSZ; idx += 128) mem0[idx] = memory[idx];
    for (int idx = tid; idx < 160; idx += 128) pz[idx] = proj[(size_t)bt * 160 + idx];
    __syncthreads();
    if (tid < SS){
        float s2 = 0.0f;
        #pragma unroll
        for (int m = 0; m < MSZ; ++m){ float v = mem0[tid*MSZ + m]; s2 = fmaf(v, v, s2); }
        rn[tid] = rsqrtf(fmaxf(s2, 1e-12f));
    }
    {   // 4 key heads: softmax over 20 then l2-normalize; plus e/a heads
        int g = tid >> 5, lm = tid & 31;
        float z = (lm < MSZ) ? pz[g*MSZ + lm] : 0.0f;
        float e = (lm < MSZ) ? __expf(z) : 0.0f;
        float ssum = e;
        #pragma unroll
        for (int o = 1; o < 32; o <<= 1) ssum += __shfl_xor(ssum, o, 32);
        float kv = e / ssum;
        float qs = kv * kv;
        #pragma unroll
        for (int o = 1; o < 32; o <<= 1) qs += __shfl_xor(qs, o, 32);
        float kn = kv * rsqrtf(fmaxf(qs, 1e-12f));
        if (lm < MSZ) khat[g][lm] = kn;
        float z2 = (lm < MSZ) ? pz[80 + g*MSZ + lm] : 0.0f;
        float v2 = (g < 2) ? sigmoidf_(z2) : z2;
        if (lm < MSZ) ea[g][lm] = v2;
    }
    __syncthreads();
    bool act = tid < SS;
    int s = tid;
    float d0 = 0.f, d1 = 0.f, dw = 0.f;
    if (act){
        #pragma unroll
        for (int m = 0; m < MSZ; ++m){
            float mv = mem0[s*MSZ + m];
            d0 = fmaf(khat[0][m], mv, d0);
            d1 = fmaf(khat[1][m], mv, d1);
            dw = fmaf(khat[2][m], mv, dw);
        }
    }
    float rns = act ? rn[s] : 0.0f;
    float e0 = act ? __expf(-rns * d0) : 0.0f;
    float e1 = act ? __expf(-rns * d1) : 0.0f;
    float ew = act ? __expf(-rns * dw) : 0.0f;
    float sum0 = blocksum128(e0, red);
    float sum1 = blocksum128(e1, red);
    float sumw = blocksum128(ew, red);
    if (act){ wrd[0][s] = e0 / sum0; wrd[1][s] = e1 / sum1; }
    float w0 = ew / sumw;
    float m1[MSZ];
    float n1 = 0.f, dkw = 0.f;
    if (act){
        #pragma unroll
        for (int m = 0; m < MSZ; ++m){
            float mv = mem0[s*MSZ + m];
            float v = fmaf(-w0 * ea[0][m], mv, mv);   // (1 - w0*e0)*mem
            v = fmaf(w0, ea[2][m], v);                // + w0*a0
            m1[m] = v;
            n1 = fmaf(v, v, n1);
            dkw = fmaf(khat[3][m], v, dkw);
        }
    }
    float rn1 = rsqrtf(fmaxf(n1, 1e-12f));
    float e1w = act ? __expf(-rn1 * dkw) : 0.0f;
    float sum1w = blocksum128(e1w, red);
    float w1 = e1w / sum1w;
    if (act){
        float buf[MSZ];
        #pragma unroll
        for (int m = 0; m < MSZ; ++m){
            float v = m1[m];
            float v2 = fmaf(-w1 * ea[1][m], v, v);
            v2 = fmaf(w1, ea[3][m], v2);
            buf[m] = v2;
        }
        float4* dst = reinterpret_cast<float4*>(outmem + ((size_t)bt * SS + s) * MSZ);
        #pragma unroll
        for (int q = 0; q < MSZ/4; ++q)
            dst[q] = make_float4(buf[4*q], buf[4*q+1], buf[4*q+2], buf[4*q+3]);
    }
    __syncthreads();
    if (tid < 2 * MSZ){
        int hd = tid / MSZ, m = tid % MSZ;
        float acc = 0.0f;
        for (int s2 = 0; s2 < SS; ++s2)
            acc = fmaf(wrd[hd][s2], mem0[s2*MSZ + m], acc);
        out[(size_t)bt * 168 + 128 + hd*MSZ + m] = acc;
    }
}

extern "C" void kernel_launch(void* const* d_in, const int* in_sizes, int n_in,
                              void* d_out, int out_size, void* d_ws, size_t ws_size,
                              hipStream_t stream){
    const float* inputs = (const float*)d_in[0];
    const float* memory = (const float*)d_in[1];
    const float* Wk     = (const float*)d_in[2];
    const float* Rk     = (const float*)d_in[3];
    const float* bias   = (const float*)d_in[4];
    const float* rWk    = (const float*)d_in[5];
    const float* rbk    = (const float*)d_in[6];
    const float* wWk    = (const float*)d_in[7];
    const float* wbk    = (const float*)d_in[8];
    const float* wWe    = (const float*)d_in[9];
    const float* wbe    = (const float*)d_in[10];
    const float* wWa    = (const float*)d_in[11];
    const float* wba    = (const float*)d_in[12];

    float* out    = (float*)d_out;
    float* outmem = out + (size_t)NROW * 168;
    // xw scratch aliases the (dead until k_heads) mem-output region
    float* xw   = outmem;
    float* ctrl = (float*)d_ws;
    float* proj = ctrl + (size_t)NROW * HH;

    k_xw  <<<NROW/8,  512, 0, stream>>>(inputs, Wk, bias, xw);
    k_scan<<<BB,      512, 0, stream>>>(xw, Rk, ctrl);
    k_proj<<<NROW/16, 320, 0, stream>>>(ctrl, rWk, rbk, wWk, wbk, wWe, wbe, wWa, wba, proj, out);
    k_heads<<<NROW,   128, 0, stream>>>(proj, memory, out, outmem);
}

// Round 7
// 319.723 us; speedup vs baseline: 1.1144x; 1.1144x over previous
//
#include <hip/hip_runtime.h>
#include <hip/hip_bf16.h>

#define BB 16
#define TT 512
#define DD 64
#define HH 128
#define SS 100
#define MSZ 20
#define NROW (BB*TT)      // 8192
#define FOURH 512

typedef __attribute__((ext_vector_type(8))) short bh8;   // 8 bf16 in 4 VGPRs
typedef __attribute__((ext_vector_type(4))) float fv4;   // MFMA accumulator

__device__ __forceinline__ float frcp(float x){ return __builtin_amdgcn_rcpf(x); }
__device__ __forceinline__ float sigmoidf_(float x){
    return frcp(1.0f + __expf(-x));
}
__device__ __forceinline__ float tanhf_(float x){
    float t = __expf(2.0f * x);
    return 1.0f - 2.0f * frcp(t + 1.0f);   // rcp(inf)=0 -> saturates to +/-1
}
__device__ __forceinline__ unsigned short f2bf(float f){
    __hip_bfloat16 h = __float2bfloat16(f);   // RNE
    union { __hip_bfloat16 b; unsigned short u; } cv; cv.b = h;
    return cv.u;
}

// ---------------- kernel A: xw = inputs @ lstm_kernel + bias ----------------
// Output layout: xw[row][n*4 + g]  (gate-interleaved per neuron -> float4/step
// loads in k_scan). row = b*TT + t, n = 0..127, g = i,f,g,o.
__global__ __launch_bounds__(512) void k_xw(const float* __restrict__ inp,
        const float* __restrict__ Wk, const float* __restrict__ bias,
        float* __restrict__ xw){
    __shared__ float in_s[8 * DD];
    int tid = threadIdx.x;
    int r0 = blockIdx.x * 8;
    in_s[tid] = inp[(size_t)r0 * DD + tid];
    __syncthreads();
    int j = tid;                       // original column g*128 + n
    int n = j & 127, g = j >> 7;
    float wreg[DD];
    #pragma unroll
    for (int d = 0; d < DD; ++d) wreg[d] = Wk[d * FOURH + j];
    float bv = bias[j];
    const float4* in4 = reinterpret_cast<const float4*>(in_s);
    #pragma unroll
    for (int r = 0; r < 8; ++r){
        float acc = bv;
        #pragma unroll
        for (int q = 0; q < DD/4; ++q){
            float4 iv = in4[r*(DD/4) + q];
            acc = fmaf(iv.x, wreg[4*q+0], acc);
            acc = fmaf(iv.y, wreg[4*q+1], acc);
            acc = fmaf(iv.z, wreg[4*q+2], acc);
            acc = fmaf(iv.w, wreg[4*q+3], acc);
        }
        xw[(size_t)(r0 + r) * FOURH + n*4 + g] = acc;
    }
}

// ---------------- kernel B: LSTM scan via MFMA, ONE block PER BATCH ---------
// (1x128 h) @ (128x512 Rk) per step as 16x16x32 MFMA, A-rows 1..15 == 0.
// R6 changes vs R5: (a) A-frag zeros hoisted out of the loop (exec-masked
// ds_read under if(rdh) only writes the 4 active lanes; the rest stay zero
// forever); (b) C-init = loop-invariant zero vector zz, xw added post-MFMA;
// (c) t-loop unrolled by 2 -> LDS buffer ping-pong is static AND the xw
// prefetch is 2 steps deep (~2 step-times > HBM latency).
__global__ __launch_bounds__(512, 2) void k_scan(const float* __restrict__ xw,
        const float* __restrict__ Rk, float* __restrict__ ctrl){
    __shared__ __align__(16) unsigned short hbuf0[HH];
    __shared__ __align__(16) unsigned short hbuf1[HH];
    const int tid = threadIdx.x;
    const int b  = blockIdx.x;   // batch
    const int w  = tid >> 6;     // wave 0..7
    const int l  = tid & 63;
    const int q  = l >> 4;       // k-group 0..3
    const int lo = l & 15;       // A-row / C-col
    if (tid < HH){ hbuf0[tid] = 0; hbuf1[tid] = 0; }
    // ---- Rk B-fragments (bf16), resident in VGPRs: 64 VGPRs ----
    bh8 bf[4][4];
    #pragma unroll
    for (int Ti = 0; Ti < 4; ++Ti){
        const int col = Ti*128 + w*16 + lo;
        #pragma unroll
        for (int kk = 0; kk < 4; ++kk){
            union { unsigned short us[8]; bh8 v; } u;
            #pragma unroll
            for (int j = 0; j < 8; ++j)
                u.us[j] = f2bf(Rk[(size_t)(kk*32 + q*8 + j)*FOURH + col]);
            bf[Ti][kk] = u.v;
        }
    }
    const bool upd = (q == 0);          // lanes 0..15: own neuron n = 16w+lo
    const bool rdh = (lo == 0);         // lanes 0,16,32,48: carry real A data
    const int  n   = w*16 + lo;
    const float4* xb4 = reinterpret_cast<const float4*>(xw) + (size_t)b*TT*HH + n;
    float* cptr = ctrl + (size_t)b*TT*HH + n;
    float c0 = 0.0f;
    float4 x0 = {0,0,0,0}, x1 = {0,0,0,0}, xp0 = {0,0,0,0}, xp1 = {0,0,0,0};
    if (upd){ x0 = xb4[0]; x1 = xb4[(size_t)HH]; }
    union AU { uint4 u; bh8 v; };
    AU a0, a1, a2, a3;                   // zero-init ONCE; only rdh lanes ever written
    a0.u = make_uint4(0u,0u,0u,0u); a1.u = a0.u; a2.u = a0.u; a3.u = a0.u;
    const fv4 zz = {0.f, 0.f, 0.f, 0.f};
    __syncthreads();

#define MFMA16() \
        fv4 z0 = __builtin_amdgcn_mfma_f32_16x16x32_bf16(a0.v, bf[0][0], zz, 0,0,0); \
        fv4 z1 = __builtin_amdgcn_mfma_f32_16x16x32_bf16(a0.v, bf[1][0], zz, 0,0,0); \
        fv4 z2 = __builtin_amdgcn_mfma_f32_16x16x32_bf16(a0.v, bf[2][0], zz, 0,0,0); \
        fv4 z3 = __builtin_amdgcn_mfma_f32_16x16x32_bf16(a0.v, bf[3][0], zz, 0,0,0); \
        z0 = __builtin_amdgcn_mfma_f32_16x16x32_bf16(a1.v, bf[0][1], z0, 0,0,0); \
        z1 = __builtin_amdgcn_mfma_f32_16x16x32_bf16(a1.v, bf[1][1], z1, 0,0,0); \
        z2 = __builtin_amdgcn_mfma_f32_16x16x32_bf16(a1.v, bf[2][1], z2, 0,0,0); \
        z3 = __builtin_amdgcn_mfma_f32_16x16x32_bf16(a1.v, bf[3][1], z3, 0,0,0); \
        z0 = __builtin_amdgcn_mfma_f32_16x16x32_bf16(a2.v, bf[0][2], z0, 0,0,0); \
        z1 = __builtin_amdgcn_mfma_f32_16x16x32_bf16(a2.v, bf[1][2], z1, 0,0,0); \
        z2 = __builtin_amdgcn_mfma_f32_16x16x32_bf16(a2.v, bf[2][2], z2, 0,0,0); \
        z3 = __builtin_amdgcn_mfma_f32_16x16x32_bf16(a2.v, bf[3][2], z3, 0,0,0); \
        z0 = __builtin_amdgcn_mfma_f32_16x16x32_bf16(a3.v, bf[0][3], z0, 0,0,0); \
        z1 = __builtin_amdgcn_mfma_f32_16x16x32_bf16(a3.v, bf[1][3], z1, 0,0,0); \
        z2 = __builtin_amdgcn_mfma_f32_16x16x32_bf16(a3.v, bf[2][3], z2, 0,0,0); \
        z3 = __builtin_amdgcn_mfma_f32_16x16x32_bf16(a3.v, bf[3][3], z3, 0,0,0);

    for (int t = 0; t < TT; t += 2){
        // ---------- substep A: time t; read hbuf0, write hbuf1 ----------
        if (rdh){
            const uint4* hr = reinterpret_cast<const uint4*>(hbuf0);
            a0.u = hr[q]; a1.u = hr[q+4]; a2.u = hr[q+8]; a3.u = hr[q+12];
        }
        {
            const int tn = (t+2 < TT) ? t+2 : TT-1;
            if (upd) xp0 = xb4[(size_t)tn * HH];
        }
        {
            MFMA16();
            if (upd){
                float ig = sigmoidf_(z0[0] + x0.x);
                float fg = sigmoidf_(z1[0] + x0.y);
                float gg = tanhf_   (z2[0] + x0.z);
                float og = sigmoidf_(z3[0] + x0.w);
                c0 = fg * c0 + ig * gg;
                float h = og * tanhf_(c0);
                cptr[(size_t)t * HH] = h;
                hbuf1[n] = f2bf(h);
            }
        }
        __syncthreads();
        // ---------- substep B: time t+1; read hbuf1, write hbuf0 ----------
        if (rdh){
            const uint4* hr = reinterpret_cast<const uint4*>(hbuf1);
            a0.u = hr[q]; a1.u = hr[q+4]; a2.u = hr[q+8]; a3.u = hr[q+12];
        }
        {
            const int tn = (t+3 < TT) ? t+3 : TT-1;
            if (upd) xp1 = xb4[(size_t)tn * HH];
        }
        {
            MFMA16();
            if (upd){
                float ig = sigmoidf_(z0[0] + x1.x);
                float fg = sigmoidf_(z1[0] + x1.y);
                float gg = tanhf_   (z2[0] + x1.z);
                float og = sigmoidf_(z3[0] + x1.w);
                c0 = fg * c0 + ig * gg;
                float h = og * tanhf_(c0);
                cptr[(size_t)(t+1) * HH] = h;
                hbuf0[n] = f2bf(h);
            }
        }
        x0 = xp0; x1 = xp1;
        __syncthreads();
    }
#undef MFMA16
}

// ---------------- kernel C: proj = ctrl @ [8 heads' W] + biases; also copies
// ctrl into out[:, 0:128] ----------------------------------------------------
__global__ __launch_bounds__(320) void k_proj(const float* __restrict__ ctrl,
        const float* __restrict__ rWk, const float* __restrict__ rbk,
        const float* __restrict__ wWk, const float* __restrict__ wbk,
        const float* __restrict__ wWe, const float* __restrict__ wbe,
        const float* __restrict__ wWa, const float* __restrict__ wba,
        float* __restrict__ proj, float* __restrict__ out){
    __shared__ float cs[16 * HH];
    int tid = threadIdx.x;
    int r0 = blockIdx.x * 16;
    for (int idx = tid; idx < 16 * HH; idx += 320){
        float v = ctrl[(size_t)r0 * HH + idx];
        cs[idx] = v;
        int r = idx >> 7, k = idx & 127;
        out[(size_t)(r0 + r) * 168 + k] = v;
    }
    __syncthreads();
    int j = tid % 160;
    int rh = tid / 160;
    int p = j / MSZ, m = j % MSZ;
    const float* Wp; const float* bp;
    switch (p){
        case 0:  Wp = rWk;            bp = rbk;        break;
        case 1:  Wp = rWk + HH*MSZ;   bp = rbk + MSZ;  break;
        case 2:  Wp = wWk;            bp = wbk;        break;
        case 3:  Wp = wWk + HH*MSZ;   bp = wbk + MSZ;  break;
        case 4:  Wp = wWe;            bp = wbe;        break;
        case 5:  Wp = wWe + HH*MSZ;   bp = wbe + MSZ;  break;
        case 6:  Wp = wWa;            bp = wba;        break;
        default: Wp = wWa + HH*MSZ;   bp = wba + MSZ;  break;
    }
    float wv[HH];
    #pragma unroll
    for (int k = 0; k < HH; ++k) wv[k] = Wp[k * MSZ + m];
    float bv = bp[m];
    #pragma unroll
    for (int r = 0; r < 8; ++r){
        int row = rh * 8 + r;
        float acc = bv;
        const float4* c4 = reinterpret_cast<const float4*>(cs + row * HH);
        #pragma unroll
        for (int q = 0; q < HH/4; ++q){
            float4 cv = c4[q];
            acc = fmaf(cv.x, wv[4*q+0], acc);
            acc = fmaf(cv.y, wv[4*q+1], acc);
            acc = fmaf(cv.z, wv[4*q+2], acc);
            acc = fmaf(cv.w, wv[4*q+3], acc);
        }
        proj[(size_t)(r0 + row) * 160 + j] = acc;
    }
}

// ---------------- kernel D: heads, one block per (b,t) ----------------------
__device__ __forceinline__ float blocksum128(float v, float* red){
    #pragma unroll
    for (int o = 1; o < 64; o <<= 1) v += __shfl_xor(v, o, 64);
    int tid = threadIdx.x;
    if ((tid & 63) == 0) red[tid >> 6] = v;
    __syncthreads();
    float s = red[0] + red[1];
    __syncthreads();
    return s;
}

__global__ __launch_bounds__(128) void k_heads(const float* __restrict__ proj,
        const float* __restrict__ memory, float* __restrict__ out,
        float* __restrict__ outmem){
    __shared__ float mem0[SS * MSZ];
    __shared__ float rn[SS];
    __shared__ float khat[4][MSZ];
    __shared__ float ea[4][MSZ];
    __shared__ float wrd[2][SS];
    __shared__ float red[2];
    __shared__ float pz[160];
    int tid = threadIdx.x;
    int bt = blockIdx.x;
    for (int idx = tid; idx < SS * MSZ; idx += 128) mem0[idx] = memory[idx];
    for (int idx = tid; idx < 160; idx += 128) pz[idx] = proj[(size_t)bt * 160 + idx];
    __syncthreads();
    if (tid < SS){
        float s2 = 0.0f;
        #pragma unroll
        for (int m = 0; m < MSZ; ++m){ float v = mem0[tid*MSZ + m]; s2 = fmaf(v, v, s2); }
        rn[tid] = rsqrtf(fmaxf(s2, 1e-12f));
    }
    {   // 4 key heads: softmax over 20 then l2-normalize; plus e/a heads
        int g = tid >> 5, lm = tid & 31;
        float z = (lm < MSZ) ? pz[g*MSZ + lm] : 0.0f;
        float e = (lm < MSZ) ? __expf(z) : 0.0f;
        float ssum = e;
        #pragma unroll
        for (int o = 1; o < 32; o <<= 1) ssum += __shfl_xor(ssum, o, 32);
        float kv = e / ssum;
        float qs = kv * kv;
        #pragma unroll
        for (int o = 1; o < 32; o <<= 1) qs += __shfl_xor(qs, o, 32);
        float kn = kv * rsqrtf(fmaxf(qs, 1e-12f));
        if (lm < MSZ) khat[g][lm] = kn;
        float z2 = (lm < MSZ) ? pz[80 + g*MSZ + lm] : 0.0f;
        float v2 = (g < 2) ? sigmoidf_(z2) : z2;
        if (lm < MSZ) ea[g][lm] = v2;
    }
    __syncthreads();
    bool act = tid < SS;
    int s = tid;
    float d0 = 0.f, d1 = 0.f, dw = 0.f;
    if (act){
        #pragma unroll
        for (int m = 0; m < MSZ; ++m){
            float mv = mem0[s*MSZ + m];
            d0 = fmaf(khat[0][m], mv, d0);
            d1 = fmaf(khat[1][m], mv, d1);
            dw = fmaf(khat[2][m], mv, dw);
        }
    }
    float rns = act ? rn[s] : 0.0f;
    float e0 = act ? __expf(-rns * d0) : 0.0f;
    float e1 = act ? __expf(-rns * d1) : 0.0f;
    float ew = act ? __expf(-rns * dw) : 0.0f;
    float sum0 = blocksum128(e0, red);
    float sum1 = blocksum128(e1, red);
    float sumw = blocksum128(ew, red);
    if (act){ wrd[0][s] = e0 / sum0; wrd[1][s] = e1 / sum1; }
    float w0 = ew / sumw;
    float m1[MSZ];
    float n1 = 0.f, dkw = 0.f;
    if (act){
        #pragma unroll
        for (int m = 0; m < MSZ; ++m){
            float mv = mem0[s*MSZ + m];
            float v = fmaf(-w0 * ea[0][m], mv, mv);   // (1 - w0*e0)*mem
            v = fmaf(w0, ea[2][m], v);                // + w0*a0
            m1[m] = v;
            n1 = fmaf(v, v, n1);
            dkw = fmaf(khat[3][m], v, dkw);
        }
    }
    float rn1 = rsqrtf(fmaxf(n1, 1e-12f));
    float e1w = act ? __expf(-rn1 * dkw) : 0.0f;
    float sum1w = blocksum128(e1w, red);
    float w1 = e1w / sum1w;
    if (act){
        float buf[MSZ];
        #pragma unroll
        for (int m = 0; m < MSZ; ++m){
            float v = m1[m];
            float v2 = fmaf(-w1 * ea[1][m], v, v);
            v2 = fmaf(w1, ea[3][m], v2);
            buf[m] = v2;
        }
        float4* dst = reinterpret_cast<float4*>(outmem + ((size_t)bt * SS + s) * MSZ);
        #pragma unroll
        for (int q = 0; q < MSZ/4; ++q)
            dst[q] = make_float4(buf[4*q], buf[4*q+1], buf[4*q+2], buf[4*q+3]);
    }
    __syncthreads();
    if (tid < 2 * MSZ){
        int hd = tid / MSZ, m = tid % MSZ;
        float acc = 0.0f;
        for (int s2 = 0; s2 < SS; ++s2)
            acc = fmaf(wrd[hd][s2], mem0[s2*MSZ + m], acc);
        out[(size_t)bt * 168 + 128 + hd*MSZ + m] = acc;
    }
}

extern "C" void kernel_launch(void* const* d_in, const int* in_sizes, int n_in,
                              void* d_out, int out_size, void* d_ws, size_t ws_size,
                              hipStream_t stream){
    const float* inputs = (const float*)d_in[0];
    const float* memory = (const float*)d_in[1];
    const float* Wk     = (const float*)d_in[2];
    const float* Rk     = (const float*)d_in[3];
    const float* bias   = (const float*)d_in[4];
    const float* rWk    = (const float*)d_in[5];
    const float* rbk    = (const float*)d_in[6];
    const float* wWk    = (const float*)d_in[7];
    const float* wbk    = (const float*)d_in[8];
    const float* wWe    = (const float*)d_in[9];
    const float* wbe    = (const float*)d_in[10];
    const float* wWa    = (const float*)d_in[11];
    const float* wba    = (const float*)d_in[12];

    float* out    = (float*)d_out;
    float* outmem = out + (size_t)NROW * 168;
    // xw scratch aliases the (dead until k_heads) mem-output region
    float* xw   = outmem;
    float* ctrl = (float*)d_ws;
    float* proj = ctrl + (size_t)NROW * HH;

    k_xw  <<<NROW/8,  512, 0, stream>>>(inputs, Wk, bias, xw);
    k_scan<<<BB,      512, 0, stream>>>(xw, Rk, ctrl);
    k_proj<<<NROW/16, 320, 0, stream>>>(ctrl, rWk, rbk, wWk, wbk, wWe, wbe, wWa, wba, proj, out);
    k_heads<<<NROW,   128, 0, stream>>>(proj, memory, out, outmem);
}

// Round 8
// 305.252 us; speedup vs baseline: 1.1673x; 1.0474x over previous
//
#include <hip/hip_runtime.h>
#include <hip/hip_bf16.h>

#define BB 16
#define TT 512
#define DD 64
#define HH 128
#define SS 100
#define MSZ 20
#define NROW (BB*TT)      // 8192
#define FOURH 512

typedef __attribute__((ext_vector_type(8))) short bh8;   // 8 bf16 in 4 VGPRs
typedef __attribute__((ext_vector_type(4))) float fv4;   // MFMA accumulator

__device__ __forceinline__ float frcp(float x){ return __builtin_amdgcn_rcpf(x); }
__device__ __forceinline__ float sigmoidf_(float x){
    return frcp(1.0f + __expf(-x));
}
__device__ __forceinline__ float tanhf_(float x){
    float t = __expf(2.0f * x);
    return 1.0f - 2.0f * frcp(t + 1.0f);   // rcp(inf)=0 -> saturates to +/-1
}
__device__ __forceinline__ unsigned short f2bf(float f){
    __hip_bfloat16 h = __float2bfloat16(f);   // RNE
    union { __hip_bfloat16 b; unsigned short u; } cv; cv.b = h;
    return cv.u;
}

// LDS-only barrier: orders ds ops across the block WITHOUT draining vmcnt —
// global stores (ctrl) and prefetch loads (xw) stay in flight across steps.
// sched_barrier(0) pins code motion (rule: inline lgkmcnt + raw s_barrier
// needs it so later ds_read/MFMA aren't hoisted above the barrier).
__device__ __forceinline__ void lds_sync(){
    asm volatile("s_waitcnt lgkmcnt(0)" ::: "memory");
    __builtin_amdgcn_s_barrier();
    __builtin_amdgcn_sched_barrier(0);
}

// ---------------- kernel A: xw = inputs @ lstm_kernel + bias ----------------
// Output layout: xw[row][n*4 + g]  (gate-interleaved per neuron -> float4/step
// loads in k_scan). row = b*TT + t, n = 0..127, g = i,f,g,o.
__global__ __launch_bounds__(512) void k_xw(const float* __restrict__ inp,
        const float* __restrict__ Wk, const float* __restrict__ bias,
        float* __restrict__ xw){
    __shared__ float in_s[8 * DD];
    int tid = threadIdx.x;
    int r0 = blockIdx.x * 8;
    in_s[tid] = inp[(size_t)r0 * DD + tid];
    __syncthreads();
    int j = tid;                       // original column g*128 + n
    int n = j & 127, g = j >> 7;
    float wreg[DD];
    #pragma unroll
    for (int d = 0; d < DD; ++d) wreg[d] = Wk[d * FOURH + j];
    float bv = bias[j];
    const float4* in4 = reinterpret_cast<const float4*>(in_s);
    #pragma unroll
    for (int r = 0; r < 8; ++r){
        float acc = bv;
        #pragma unroll
        for (int q = 0; q < DD/4; ++q){
            float4 iv = in4[r*(DD/4) + q];
            acc = fmaf(iv.x, wreg[4*q+0], acc);
            acc = fmaf(iv.y, wreg[4*q+1], acc);
            acc = fmaf(iv.z, wreg[4*q+2], acc);
            acc = fmaf(iv.w, wreg[4*q+3], acc);
        }
        xw[(size_t)(r0 + r) * FOURH + n*4 + g] = acc;
    }
}

// ---------------- kernel B: LSTM scan via MFMA, ONE block PER BATCH ---------
// (1x128 h) @ (128x512 Rk) per step as 16x16x32 MFMA, A-rows 1..15 == 0.
// R7 change vs R6: __syncthreads() -> lds_sync() (lgkmcnt-only barrier).
// The compiler's __syncthreads drains vmcnt(0) every step, serializing the
// ctrl store (~300 cyc) and killing the 2-deep xw prefetch. Only LDS needs
// ordering at the barrier (h exchange); global ops are lane-private.
__global__ __launch_bounds__(512, 2) void k_scan(const float* __restrict__ xw,
        const float* __restrict__ Rk, float* __restrict__ ctrl){
    __shared__ __align__(16) unsigned short hbuf0[HH];
    __shared__ __align__(16) unsigned short hbuf1[HH];
    const int tid = threadIdx.x;
    const int b  = blockIdx.x;   // batch
    const int w  = tid >> 6;     // wave 0..7
    const int l  = tid & 63;
    const int q  = l >> 4;       // k-group 0..3
    const int lo = l & 15;       // A-row / C-col
    if (tid < HH){ hbuf0[tid] = 0; hbuf1[tid] = 0; }
    // ---- Rk B-fragments (bf16), resident in VGPRs: 64 VGPRs ----
    bh8 bf[4][4];
    #pragma unroll
    for (int Ti = 0; Ti < 4; ++Ti){
        const int col = Ti*128 + w*16 + lo;
        #pragma unroll
        for (int kk = 0; kk < 4; ++kk){
            union { unsigned short us[8]; bh8 v; } u;
            #pragma unroll
            for (int j = 0; j < 8; ++j)
                u.us[j] = f2bf(Rk[(size_t)(kk*32 + q*8 + j)*FOURH + col]);
            bf[Ti][kk] = u.v;
        }
    }
    const bool upd = (q == 0);          // lanes 0..15: own neuron n = 16w+lo
    const bool rdh = (lo == 0);         // lanes 0,16,32,48: carry real A data
    const int  n   = w*16 + lo;
    const float4* xb4 = reinterpret_cast<const float4*>(xw) + (size_t)b*TT*HH + n;
    float* cptr = ctrl + (size_t)b*TT*HH + n;
    float c0 = 0.0f;
    float4 x0 = {0,0,0,0}, x1 = {0,0,0,0}, xp0 = {0,0,0,0}, xp1 = {0,0,0,0};
    if (upd){ x0 = xb4[0]; x1 = xb4[(size_t)HH]; }
    union AU { uint4 u; bh8 v; };
    AU a0, a1, a2, a3;                   // zero-init ONCE; only rdh lanes ever written
    a0.u = make_uint4(0u,0u,0u,0u); a1.u = a0.u; a2.u = a0.u; a3.u = a0.u;
    const fv4 zz = {0.f, 0.f, 0.f, 0.f};
    __syncthreads();

#define MFMA16() \
        fv4 z0 = __builtin_amdgcn_mfma_f32_16x16x32_bf16(a0.v, bf[0][0], zz, 0,0,0); \
        fv4 z1 = __builtin_amdgcn_mfma_f32_16x16x32_bf16(a0.v, bf[1][0], zz, 0,0,0); \
        fv4 z2 = __builtin_amdgcn_mfma_f32_16x16x32_bf16(a0.v, bf[2][0], zz, 0,0,0); \
        fv4 z3 = __builtin_amdgcn_mfma_f32_16x16x32_bf16(a0.v, bf[3][0], zz, 0,0,0); \
        z0 = __builtin_amdgcn_mfma_f32_16x16x32_bf16(a1.v, bf[0][1], z0, 0,0,0); \
        z1 = __builtin_amdgcn_mfma_f32_16x16x32_bf16(a1.v, bf[1][1], z1, 0,0,0); \
        z2 = __builtin_amdgcn_mfma_f32_16x16x32_bf16(a1.v, bf[2][1], z2, 0,0,0); \
        z3 = __builtin_amdgcn_mfma_f32_16x16x32_bf16(a1.v, bf[3][1], z3, 0,0,0); \
        z0 = __builtin_amdgcn_mfma_f32_16x16x32_bf16(a2.v, bf[0][2], z0, 0,0,0); \
        z1 = __builtin_amdgcn_mfma_f32_16x16x32_bf16(a2.v, bf[1][2], z1, 0,0,0); \
        z2 = __builtin_amdgcn_mfma_f32_16x16x32_bf16(a2.v, bf[2][2], z2, 0,0,0); \
        z3 = __builtin_amdgcn_mfma_f32_16x16x32_bf16(a2.v, bf[3][2], z3, 0,0,0); \
        z0 = __builtin_amdgcn_mfma_f32_16x16x32_bf16(a3.v, bf[0][3], z0, 0,0,0); \
        z1 = __builtin_amdgcn_mfma_f32_16x16x32_bf16(a3.v, bf[1][3], z1, 0,0,0); \
        z2 = __builtin_amdgcn_mfma_f32_16x16x32_bf16(a3.v, bf[2][3], z2, 0,0,0); \
        z3 = __builtin_amdgcn_mfma_f32_16x16x32_bf16(a3.v, bf[3][3], z3, 0,0,0);

    for (int t = 0; t < TT; t += 2){
        // ---------- substep A: time t; read hbuf0, write hbuf1 ----------
        if (rdh){
            const uint4* hr = reinterpret_cast<const uint4*>(hbuf0);
            a0.u = hr[q]; a1.u = hr[q+4]; a2.u = hr[q+8]; a3.u = hr[q+12];
        }
        {
            const int tn = (t+2 < TT) ? t+2 : TT-1;
            if (upd) xp0 = xb4[(size_t)tn * HH];
        }
        {
            MFMA16();
            if (upd){
                float ig = sigmoidf_(z0[0] + x0.x);
                float fg = sigmoidf_(z1[0] + x0.y);
                float gg = tanhf_   (z2[0] + x0.z);
                float og = sigmoidf_(z3[0] + x0.w);
                c0 = fg * c0 + ig * gg;
                float h = og * tanhf_(c0);
                cptr[(size_t)t * HH] = h;
                hbuf1[n] = f2bf(h);
            }
        }
        lds_sync();
        // ---------- substep B: time t+1; read hbuf1, write hbuf0 ----------
        if (rdh){
            const uint4* hr = reinterpret_cast<const uint4*>(hbuf1);
            a0.u = hr[q]; a1.u = hr[q+4]; a2.u = hr[q+8]; a3.u = hr[q+12];
        }
        {
            const int tn = (t+3 < TT) ? t+3 : TT-1;
            if (upd) xp1 = xb4[(size_t)tn * HH];
        }
        {
            MFMA16();
            if (upd){
                float ig = sigmoidf_(z0[0] + x1.x);
                float fg = sigmoidf_(z1[0] + x1.y);
                float gg = tanhf_   (z2[0] + x1.z);
                float og = sigmoidf_(z3[0] + x1.w);
                c0 = fg * c0 + ig * gg;
                float h = og * tanhf_(c0);
                cptr[(size_t)(t+1) * HH] = h;
                hbuf0[n] = f2bf(h);
            }
        }
        x0 = xp0; x1 = xp1;
        lds_sync();
    }
#undef MFMA16
}

// ---------------- kernel C: proj = ctrl @ [8 heads' W] + biases; also copies
// ctrl into out[:, 0:128] ----------------------------------------------------
__global__ __launch_bounds__(320) void k_proj(const float* __restrict__ ctrl,
        const float* __restrict__ rWk, const float* __restrict__ rbk,
        const float* __restrict__ wWk, const float* __restrict__ wbk,
        const float* __restrict__ wWe, const float* __restrict__ wbe,
        const float* __restrict__ wWa, const float* __restrict__ wba,
        float* __restrict__ proj, float* __restrict__ out){
    __shared__ float cs[16 * HH];
    int tid = threadIdx.x;
    int r0 = blockIdx.x * 16;
    for (int idx = tid; idx < 16 * HH; idx += 320){
        float v = ctrl[(size_t)r0 * HH + idx];
        cs[idx] = v;
        int r = idx >> 7, k = idx & 127;
        out[(size_t)(r0 + r) * 168 + k] = v;
    }
    __syncthreads();
    int j = tid % 160;
    int rh = tid / 160;
    int p = j / MSZ, m = j % MSZ;
    const float* Wp; const float* bp;
    switch (p){
        case 0:  Wp = rWk;            bp = rbk;        break;
        case 1:  Wp = rWk + HH*MSZ;   bp = rbk + MSZ;  break;
        case 2:  Wp = wWk;            bp = wbk;        break;
        case 3:  Wp = wWk + HH*MSZ;   bp = wbk + MSZ;  break;
        case 4:  Wp = wWe;            bp = wbe;        break;
        case 5:  Wp = wWe + HH*MSZ;   bp = wbe + MSZ;  break;
        case 6:  Wp = wWa;            bp = wba;        break;
        default: Wp = wWa + HH*MSZ;   bp = wba + MSZ;  break;
    }
    float wv[HH];
    #pragma unroll
    for (int k = 0; k < HH; ++k) wv[k] = Wp[k * MSZ + m];
    float bv = bp[m];
    #pragma unroll
    for (int r = 0; r < 8; ++r){
        int row = rh * 8 + r;
        float acc = bv;
        const float4* c4 = reinterpret_cast<const float4*>(cs + row * HH);
        #pragma unroll
        for (int q = 0; q < HH/4; ++q){
            float4 cv = c4[q];
            acc = fmaf(cv.x, wv[4*q+0], acc);
            acc = fmaf(cv.y, wv[4*q+1], acc);
            acc = fmaf(cv.z, wv[4*q+2], acc);
            acc = fmaf(cv.w, wv[4*q+3], acc);
        }
        proj[(size_t)(r0 + row) * 160 + j] = acc;
    }
}

// ---------------- kernel D: heads, one block per (b,t) ----------------------
__device__ __forceinline__ float blocksum128(float v, float* red){
    #pragma unroll
    for (int o = 1; o < 64; o <<= 1) v += __shfl_xor(v, o, 64);
    int tid = threadIdx.x;
    if ((tid & 63) == 0) red[tid >> 6] = v;
    __syncthreads();
    float s = red[0] + red[1];
    __syncthreads();
    return s;
}

__global__ __launch_bounds__(128) void k_heads(const float* __restrict__ proj,
        const float* __restrict__ memory, float* __restrict__ out,
        float* __restrict__ outmem){
    __shared__ float mem0[SS * MSZ];
    __shared__ float rn[SS];
    __shared__ float khat[4][MSZ];
    __shared__ float ea[4][MSZ];
    __shared__ float wrd[2][SS];
    __shared__ float red[2];
    __shared__ float pz[160];
    int tid = threadIdx.x;
    int bt = blockIdx.x;
    for (int idx = tid; idx < SS * MSZ; idx += 128) mem0[idx] = memory[idx];
    for (int idx = tid; idx < 160; idx += 128) pz[idx] = proj[(size_t)bt * 160 + idx];
    __syncthreads();
    if (tid < SS){
        float s2 = 0.0f;
        #pragma unroll
        for (int m = 0; m < MSZ; ++m){ float v = mem0[tid*MSZ + m]; s2 = fmaf(v, v, s2); }
        rn[tid] = rsqrtf(fmaxf(s2, 1e-12f));
    }
    {   // 4 key heads: softmax over 20 then l2-normalize; plus e/a heads
        int g = tid >> 5, lm = tid & 31;
        float z = (lm < MSZ) ? pz[g*MSZ + lm] : 0.0f;
        float e = (lm < MSZ) ? __expf(z) : 0.0f;
        float ssum = e;
        #pragma unroll
        for (int o = 1; o < 32; o <<= 1) ssum += __shfl_xor(ssum, o, 32);
        float kv = e / ssum;
        float qs = kv * kv;
        #pragma unroll
        for (int o = 1; o < 32; o <<= 1) qs += __shfl_xor(qs, o, 32);
        float kn = kv * rsqrtf(fmaxf(qs, 1e-12f));
        if (lm < MSZ) khat[g][lm] = kn;
        float z2 = (lm < MSZ) ? pz[80 + g*MSZ + lm] : 0.0f;
        float v2 = (g < 2) ? sigmoidf_(z2) : z2;
        if (lm < MSZ) ea[g][lm] = v2;
    }
    __syncthreads();
    bool act = tid < SS;
    int s = tid;
    float d0 = 0.f, d1 = 0.f, dw = 0.f;
    if (act){
        #pragma unroll
        for (int m = 0; m < MSZ; ++m){
            float mv = mem0[s*MSZ + m];
            d0 = fmaf(khat[0][m], mv, d0);
            d1 = fmaf(khat[1][m], mv, d1);
            dw = fmaf(khat[2][m], mv, dw);
        }
    }
    float rns = act ? rn[s] : 0.0f;
    float e0 = act ? __expf(-rns * d0) : 0.0f;
    float e1 = act ? __expf(-rns * d1) : 0.0f;
    float ew = act ? __expf(-rns * dw) : 0.0f;
    float sum0 = blocksum128(e0, red);
    float sum1 = blocksum128(e1, red);
    float sumw = blocksum128(ew, red);
    if (act){ wrd[0][s] = e0 / sum0; wrd[1][s] = e1 / sum1; }
    float w0 = ew / sumw;
    float m1[MSZ];
    float n1 = 0.f, dkw = 0.f;
    if (act){
        #pragma unroll
        for (int m = 0; m < MSZ; ++m){
            float mv = mem0[s*MSZ + m];
            float v = fmaf(-w0 * ea[0][m], mv, mv);   // (1 - w0*e0)*mem
            v = fmaf(w0, ea[2][m], v);                // + w0*a0
            m1[m] = v;
            n1 = fmaf(v, v, n1);
            dkw = fmaf(khat[3][m], v, dkw);
        }
    }
    float rn1 = rsqrtf(fmaxf(n1, 1e-12f));
    float e1w = act ? __expf(-rn1 * dkw) : 0.0f;
    float sum1w = blocksum128(e1w, red);
    float w1 = e1w / sum1w;
    if (act){
        float buf[MSZ];
        #pragma unroll
        for (int m = 0; m < MSZ; ++m){
            float v = m1[m];
            float v2 = fmaf(-w1 * ea[1][m], v, v);
            v2 = fmaf(w1, ea[3][m], v2);
            buf[m] = v2;
        }
        float4* dst = reinterpret_cast<float4*>(outmem + ((size_t)bt * SS + s) * MSZ);
        #pragma unroll
        for (int q = 0; q < MSZ/4; ++q)
            dst[q] = make_float4(buf[4*q], buf[4*q+1], buf[4*q+2], buf[4*q+3]);
    }
    __syncthreads();
    if (tid < 2 * MSZ){
        int hd = tid / MSZ, m = tid % MSZ;
        float acc = 0.0f;
        for (int s2 = 0; s2 < SS; ++s2)
            acc = fmaf(wrd[hd][s2], mem0[s2*MSZ + m], acc);
        out[(size_t)bt * 168 + 128 + hd*MSZ + m] = acc;
    }
}

extern "C" void kernel_launch(void* const* d_in, const int* in_sizes, int n_in,
                              void* d_out, int out_size, void* d_ws, size_t ws_size,
                              hipStream_t stream){
    const float* inputs = (const float*)d_in[0];
    const float* memory = (const float*)d_in[1];
    const float* Wk     = (const float*)d_in[2];
    const float* Rk     = (const float*)d_in[3];
    const float* bias   = (const float*)d_in[4];
    const float* rWk    = (const float*)d_in[5];
    const float* rbk    = (const float*)d_in[6];
    const float* wWk    = (const float*)d_in[7];
    const float* wbk    = (const float*)d_in[8];
    const float* wWe    = (const float*)d_in[9];
    const float* wbe    = (const float*)d_in[10];
    const float* wWa    = (const float*)d_in[11];
    const float* wba    = (const float*)d_in[12];

    float* out    = (float*)d_out;
    float* outmem = out + (size_t)NROW * 168;
    // xw scratch aliases the (dead until k_heads) mem-output region
    float* xw   = outmem;
    float* ctrl = (float*)d_ws;
    float* proj = ctrl + (size_t)NROW * HH;

    k_xw  <<<NROW/8,  512, 0, stream>>>(inputs, Wk, bias, xw);
    k_scan<<<BB,      512, 0, stream>>>(xw, Rk, ctrl);
    k_proj<<<NROW/16, 320, 0, stream>>>(ctrl, rWk, rbk, wWk, wbk, wWe, wbe, wWa, wba, proj, out);
    k_heads<<<NROW,   128, 0, stream>>>(proj, memory, out, outmem);
}

// Round 10
// 304.222 us; speedup vs baseline: 1.1712x; 1.0034x over previous
//
#include <hip/hip_runtime.h>
#include <hip/hip_bf16.h>

#define BB 16
#define TT 512
#define DD 64
#define HH 128
#define SS 100
#define MSZ 20
#define NROW (BB*TT)      // 8192
#define FOURH 512

typedef __attribute__((ext_vector_type(8))) short bh8;   // 8 bf16 in 4 VGPRs
typedef __attribute__((ext_vector_type(4))) float fv4;   // MFMA accumulator

__device__ __forceinline__ float frcp(float x){ return __builtin_amdgcn_rcpf(x); }
__device__ __forceinline__ float sigmoidf_(float x){
    return frcp(1.0f + __expf(-x));
}
__device__ __forceinline__ float tanhf_(float x){
    float t = __expf(2.0f * x);
    return 1.0f - 2.0f * frcp(t + 1.0f);   // rcp(inf)=0 -> saturates to +/-1
}
__device__ __forceinline__ unsigned short f2bf(float f){
    __hip_bfloat16 h = __float2bfloat16(f);   // RNE
    union { __hip_bfloat16 b; unsigned short u; } cv; cv.b = h;
    return cv.u;
}

// LDS-only barrier: orders ds ops across the block WITHOUT draining vmcnt —
// global stores (ctrl) and prefetch loads (xw) stay in flight across steps.
__device__ __forceinline__ void lds_sync(){
    asm volatile("s_waitcnt lgkmcnt(0)" ::: "memory");
    __builtin_amdgcn_s_barrier();
    __builtin_amdgcn_sched_barrier(0);
}

// ---------------- kernel A: xw = inputs @ lstm_kernel + bias ----------------
// Output layout: xw[row][n*4 + g]  (gate-interleaved per neuron -> float4/step
// loads in k_scan). row = b*TT + t, n = 0..127, g = i,f,g,o.
__global__ __launch_bounds__(512) void k_xw(const float* __restrict__ inp,
        const float* __restrict__ Wk, const float* __restrict__ bias,
        float* __restrict__ xw){
    __shared__ float in_s[8 * DD];
    int tid = threadIdx.x;
    int r0 = blockIdx.x * 8;
    in_s[tid] = inp[(size_t)r0 * DD + tid];
    __syncthreads();
    int j = tid;                       // original column g*128 + n
    int n = j & 127, g = j >> 7;
    float wreg[DD];
    #pragma unroll
    for (int d = 0; d < DD; ++d) wreg[d] = Wk[d * FOURH + j];
    float bv = bias[j];
    const float4* in4 = reinterpret_cast<const float4*>(in_s);
    #pragma unroll
    for (int r = 0; r < 8; ++r){
        float acc = bv;
        #pragma unroll
        for (int q = 0; q < DD/4; ++q){
            float4 iv = in4[r*(DD/4) + q];
            acc = fmaf(iv.x, wreg[4*q+0], acc);
            acc = fmaf(iv.y, wreg[4*q+1], acc);
            acc = fmaf(iv.z, wreg[4*q+2], acc);
            acc = fmaf(iv.w, wreg[4*q+3], acc);
        }
        xw[(size_t)(r0 + r) * FOURH + n*4 + g] = acc;
    }
}

// ---------------- kernel B: LSTM scan via MFMA, ONE block PER BATCH ---------
// EXACT R7 structure (proven stable across graph replays): 8 waves, unroll 2,
// clamped 2-deep xw prefetch, lds_sync (lgkmcnt-only barrier), A-rows 1..15
// structurally zero (only (l&15)==0 lanes read h from LDS; others keep
// register zeros), xw float4 added post-MFMA on upd lanes.
__global__ __launch_bounds__(512, 2) void k_scan(const float* __restrict__ xw,
        const float* __restrict__ Rk, float* __restrict__ ctrl){
    __shared__ __align__(16) unsigned short hbuf0[HH];
    __shared__ __align__(16) unsigned short hbuf1[HH];
    const int tid = threadIdx.x;
    const int b  = blockIdx.x;   // batch
    const int w  = tid >> 6;     // wave 0..7
    const int l  = tid & 63;
    const int q  = l >> 4;       // k-group 0..3
    const int lo = l & 15;       // A-row / C-col
    if (tid < HH){ hbuf0[tid] = 0; hbuf1[tid] = 0; }
    // ---- Rk B-fragments (bf16), resident in VGPRs: 64 VGPRs ----
    bh8 bf[4][4];
    #pragma unroll
    for (int Ti = 0; Ti < 4; ++Ti){
        const int col = Ti*128 + w*16 + lo;
        #pragma unroll
        for (int kk = 0; kk < 4; ++kk){
            union { unsigned short us[8]; bh8 v; } u;
            #pragma unroll
            for (int j = 0; j < 8; ++j)
                u.us[j] = f2bf(Rk[(size_t)(kk*32 + q*8 + j)*FOURH + col]);
            bf[Ti][kk] = u.v;
        }
    }
    const bool upd = (q == 0);          // lanes 0..15: own neuron n = 16w+lo
    const bool rdh = (lo == 0);         // lanes 0,16,32,48: carry real A data
    const int  n   = w*16 + lo;
    const float4* xb4 = reinterpret_cast<const float4*>(xw) + (size_t)b*TT*HH + n;
    float* cptr = ctrl + (size_t)b*TT*HH + n;
    float c0 = 0.0f;
    float4 x0 = {0,0,0,0}, x1 = {0,0,0,0}, xp0 = {0,0,0,0}, xp1 = {0,0,0,0};
    if (upd){ x0 = xb4[0]; x1 = xb4[(size_t)HH]; }
    union AU { uint4 u; bh8 v; };
    AU a0, a1, a2, a3;                   // zero-init ONCE; only rdh lanes ever written
    a0.u = make_uint4(0u,0u,0u,0u); a1.u = a0.u; a2.u = a0.u; a3.u = a0.u;
    const fv4 zz = {0.f, 0.f, 0.f, 0.f};
    __syncthreads();

#define MFMA16() \
        fv4 z0 = __builtin_amdgcn_mfma_f32_16x16x32_bf16(a0.v, bf[0][0], zz, 0,0,0); \
        fv4 z1 = __builtin_amdgcn_mfma_f32_16x16x32_bf16(a0.v, bf[1][0], zz, 0,0,0); \
        fv4 z2 = __builtin_amdgcn_mfma_f32_16x16x32_bf16(a0.v, bf[2][0], zz, 0,0,0); \
        fv4 z3 = __builtin_amdgcn_mfma_f32_16x16x32_bf16(a0.v, bf[3][0], zz, 0,0,0); \
        z0 = __builtin_amdgcn_mfma_f32_16x16x32_bf16(a1.v, bf[0][1], z0, 0,0,0); \
        z1 = __builtin_amdgcn_mfma_f32_16x16x32_bf16(a1.v, bf[1][1], z1, 0,0,0); \
        z2 = __builtin_amdgcn_mfma_f32_16x16x32_bf16(a1.v, bf[2][1], z2, 0,0,0); \
        z3 = __builtin_amdgcn_mfma_f32_16x16x32_bf16(a1.v, bf[3][1], z3, 0,0,0); \
        z0 = __builtin_amdgcn_mfma_f32_16x16x32_bf16(a2.v, bf[0][2], z0, 0,0,0); \
        z1 = __builtin_amdgcn_mfma_f32_16x16x32_bf16(a2.v, bf[1][2], z1, 0,0,0); \
        z2 = __builtin_amdgcn_mfma_f32_16x16x32_bf16(a2.v, bf[2][2], z2, 0,0,0); \
        z3 = __builtin_amdgcn_mfma_f32_16x16x32_bf16(a2.v, bf[3][2], z3, 0,0,0); \
        z0 = __builtin_amdgcn_mfma_f32_16x16x32_bf16(a3.v, bf[0][3], z0, 0,0,0); \
        z1 = __builtin_amdgcn_mfma_f32_16x16x32_bf16(a3.v, bf[1][3], z1, 0,0,0); \
        z2 = __builtin_amdgcn_mfma_f32_16x16x32_bf16(a3.v, bf[2][3], z2, 0,0,0); \
        z3 = __builtin_amdgcn_mfma_f32_16x16x32_bf16(a3.v, bf[3][3], z3, 0,0,0);

    for (int t = 0; t < TT; t += 2){
        // ---------- substep A: time t; read hbuf0, write hbuf1 ----------
        if (rdh){
            const uint4* hr = reinterpret_cast<const uint4*>(hbuf0);
            a0.u = hr[q]; a1.u = hr[q+4]; a2.u = hr[q+8]; a3.u = hr[q+12];
        }
        {
            const int tn = (t+2 < TT) ? t+2 : TT-1;
            if (upd) xp0 = xb4[(size_t)tn * HH];
        }
        {
            MFMA16();
            if (upd){
                float ig = sigmoidf_(z0[0] + x0.x);
                float fg = sigmoidf_(z1[0] + x0.y);
                float gg = tanhf_   (z2[0] + x0.z);
                float og = sigmoidf_(z3[0] + x0.w);
                c0 = fg * c0 + ig * gg;
                float h = og * tanhf_(c0);
                cptr[(size_t)t * HH] = h;
                hbuf1[n] = f2bf(h);
            }
        }
        lds_sync();
        // ---------- substep B: time t+1; read hbuf1, write hbuf0 ----------
        if (rdh){
            const uint4* hr = reinterpret_cast<const uint4*>(hbuf1);
            a0.u = hr[q]; a1.u = hr[q+4]; a2.u = hr[q+8]; a3.u = hr[q+12];
        }
        {
            const int tn = (t+3 < TT) ? t+3 : TT-1;
            if (upd) xp1 = xb4[(size_t)tn * HH];
        }
        {
            MFMA16();
            if (upd){
                float ig = sigmoidf_(z0[0] + x1.x);
                float fg = sigmoidf_(z1[0] + x1.y);
                float gg = tanhf_   (z2[0] + x1.z);
                float og = sigmoidf_(z3[0] + x1.w);
                c0 = fg * c0 + ig * gg;
                float h = og * tanhf_(c0);
                cptr[(size_t)(t+1) * HH] = h;
                hbuf0[n] = f2bf(h);
            }
        }
        x0 = xp0; x1 = xp1;
        lds_sync();
    }
#undef MFMA16
}

// ---------------- kernel D: heads (k_proj fused in), one block per (b,t) ----
__device__ __forceinline__ float blocksum128(float v, float* red){
    #pragma unroll
    for (int o = 1; o < 64; o <<= 1) v += __shfl_xor(v, o, 64);
    int tid = threadIdx.x;
    if ((tid & 63) == 0) red[tid >> 6] = v;
    __syncthreads();
    float s = red[0] + red[1];
    __syncthreads();
    return s;
}

__global__ __launch_bounds__(128) void k_heads(const float* __restrict__ ctrl,
        const float* __restrict__ memory,
        const float* __restrict__ rWk, const float* __restrict__ rbk,
        const float* __restrict__ wWk, const float* __restrict__ wbk,
        const float* __restrict__ wWe, const float* __restrict__ wbe,
        const float* __restrict__ wWa, const float* __restrict__ wba,
        float* __restrict__ out, float* __restrict__ outmem){
    __shared__ float mem0[SS * MSZ];
    __shared__ float cs[HH];
    __shared__ float rn[SS];
    __shared__ float khat[4][MSZ];
    __shared__ float ea[4][MSZ];
    __shared__ float wrd[2][SS];
    __shared__ float red[2];
    __shared__ float pz[160];
    int tid = threadIdx.x;
    int bt = blockIdx.x;
    for (int idx = tid; idx < SS * MSZ; idx += 128) mem0[idx] = memory[idx];
    if (tid < HH){
        float v = ctrl[(size_t)bt * HH + tid];
        cs[tid] = v;
        out[(size_t)bt * 168 + tid] = v;   // ctrl copy into out[:,0:128]
    }
    __syncthreads();
    // per-slot L2 norms of memory (uses mem0)
    if (tid < SS){
        float s2 = 0.0f;
        #pragma unroll
        for (int m = 0; m < MSZ; ++m){ float v = mem0[tid*MSZ + m]; s2 = fmaf(v, v, s2); }
        rn[tid] = rsqrtf(fmaxf(s2, 1e-12f));
    }
    // ---- fused proj: pz[j] = ctrl_row . W[:,j] + b  (j = 0..159) ----
    // weights total 80 KB, shared by all 8192 blocks -> L2/L3 resident.
    for (int j = tid; j < 160; j += 128){
        int p = j / MSZ, m = j % MSZ;
        const float* Wp; const float* bp;
        switch (p){
            case 0:  Wp = rWk;            bp = rbk;        break;
            case 1:  Wp = rWk + HH*MSZ;   bp = rbk + MSZ;  break;
            case 2:  Wp = wWk;            bp = wbk;        break;
            case 3:  Wp = wWk + HH*MSZ;   bp = wbk + MSZ;  break;
            case 4:  Wp = wWe;            bp = wbe;        break;
            case 5:  Wp = wWe + HH*MSZ;   bp = wbe + MSZ;  break;
            case 6:  Wp = wWa;            bp = wba;        break;
            default: Wp = wWa + HH*MSZ;   bp = wba + MSZ;  break;
        }
        float acc = bp[m];
        const float* wcol = Wp + m;
        #pragma unroll 16
        for (int k = 0; k < HH; ++k)
            acc = fmaf(cs[k], wcol[k*MSZ], acc);   // cs[k]: LDS broadcast
        pz[j] = acc;
    }
    __syncthreads();
    {   // 4 key heads: softmax over 20 then l2-normalize; plus e/a heads
        int g = tid >> 5, lm = tid & 31;
        float z = (lm < MSZ) ? pz[g*MSZ + lm] : 0.0f;
        float e = (lm < MSZ) ? __expf(z) : 0.0f;
        float ssum = e;
        #pragma unroll
        for (int o = 1; o < 32; o <<= 1) ssum += __shfl_xor(ssum, o, 32);
        float kv = e / ssum;
        float qs = kv * kv;
        #pragma unroll
        for (int o = 1; o < 32; o <<= 1) qs += __shfl_xor(qs, o, 32);
        float kn = kv * rsqrtf(fmaxf(qs, 1e-12f));
        if (lm < MSZ) khat[g][lm] = kn;
        float z2 = (lm < MSZ) ? pz[80 + g*MSZ + lm] : 0.0f;
        float v2 = (g < 2) ? sigmoidf_(z2) : z2;
        if (lm < MSZ) ea[g][lm] = v2;
    }
    __syncthreads();
    bool act = tid < SS;
    int s = tid;
    float d0 = 0.f, d1 = 0.f, dw = 0.f;
    if (act){
        #pragma unroll
        for (int m = 0; m < MSZ; ++m){
            float mv = mem0[s*MSZ + m];
            d0 = fmaf(khat[0][m], mv, d0);
            d1 = fmaf(khat[1][m], mv, d1);
            dw = fmaf(khat[2][m], mv, dw);
        }
    }
    float rns = act ? rn[s] : 0.0f;
    float e0 = act ? __expf(-rns * d0) : 0.0f;
    float e1 = act ? __expf(-rns * d1) : 0.0f;
    float ew = act ? __expf(-rns * dw) : 0.0f;
    float sum0 = blocksum128(e0, red);
    float sum1 = blocksum128(e1, red);
    float sumw = blocksum128(ew, red);
    if (act){ wrd[0][s] = e0 / sum0; wrd[1][s] = e1 / sum1; }
    float w0 = ew / sumw;
    float m1[MSZ];
    float n1 = 0.f, dkw = 0.f;
    if (act){
        #pragma unroll
        for (int m = 0; m < MSZ; ++m){
            float mv = mem0[s*MSZ + m];
            float v = fmaf(-w0 * ea[0][m], mv, mv);   // (1 - w0*e0)*mem
            v = fmaf(w0, ea[2][m], v);                // + w0*a0
            m1[m] = v;
            n1 = fmaf(v, v, n1);
            dkw = fmaf(khat[3][m], v, dkw);
        }
    }
    float rn1 = rsqrtf(fmaxf(n1, 1e-12f));
    float e1w = act ? __expf(-rn1 * dkw) : 0.0f;
    float sum1w = blocksum128(e1w, red);
    float w1 = e1w / sum1w;
    if (act){
        float buf[MSZ];
        #pragma unroll
        for (int m = 0; m < MSZ; ++m){
            float v = m1[m];
            float v2 = fmaf(-w1 * ea[1][m], v, v);
            v2 = fmaf(w1, ea[3][m], v2);
            buf[m] = v2;
        }
        float4* dst = reinterpret_cast<float4*>(outmem + ((size_t)bt * SS + s) * MSZ);
        #pragma unroll
        for (int q = 0; q < MSZ/4; ++q)
            dst[q] = make_float4(buf[4*q], buf[4*q+1], buf[4*q+2], buf[4*q+3]);
    }
    __syncthreads();
    if (tid < 2 * MSZ){
        int hd = tid / MSZ, m = tid % MSZ;
        float acc = 0.0f;
        for (int s2 = 0; s2 < SS; ++s2)
            acc = fmaf(wrd[hd][s2], mem0[s2*MSZ + m], acc);
        out[(size_t)bt * 168 + 128 + hd*MSZ + m] = acc;
    }
}

extern "C" void kernel_launch(void* const* d_in, const int* in_sizes, int n_in,
                              void* d_out, int out_size, void* d_ws, size_t ws_size,
                              hipStream_t stream){
    const float* inputs = (const float*)d_in[0];
    const float* memory = (const float*)d_in[1];
    const float* Wk     = (const float*)d_in[2];
    const float* Rk     = (const float*)d_in[3];
    const float* bias   = (const float*)d_in[4];
    const float* rWk    = (const float*)d_in[5];
    const float* rbk    = (const float*)d_in[6];
    const float* wWk    = (const float*)d_in[7];
    const float* wbk    = (const float*)d_in[8];
    const float* wWe    = (const float*)d_in[9];
    const float* wbe    = (const float*)d_in[10];
    const float* wWa    = (const float*)d_in[11];
    const float* wba    = (const float*)d_in[12];

    float* out    = (float*)d_out;
    float* outmem = out + (size_t)NROW * 168;
    // xw scratch aliases the (dead until k_heads) mem-output region
    float* xw   = outmem;
    float* ctrl = (float*)d_ws;

    k_xw   <<<NROW/8, 512, 0, stream>>>(inputs, Wk, bias, xw);
    k_scan <<<BB,     512, 0, stream>>>(xw, Rk, ctrl);
    k_heads<<<NROW,   128, 0, stream>>>(ctrl, memory,
                                        rWk, rbk, wWk, wbk, wWe, wbe, wWa, wba,
                                        out, outmem);
}